// Round 6
// baseline (590.197 us; speedup 1.0000x reference)
//
#include <hip/hip_runtime.h>
#include <hip/hip_fp16.h>

#define DIM 64
#define BNODE_SHIFT 8                 // 256 nodes per bucket
#define BNODE (1 << BNODE_SHIFT)
#define MAXNB 1024                    // max buckets (N <= 262144)
#define BCAP_SHIFT 13                 // 8192-edge capacity per bucket (mean 5115, sigma ~72)
#define BCAP (1 << BCAP_SHIFT)
#define BIN_CHUNK 32768               // edges per block: ~42-edge (168B) runs per bucket
                                      // -> full-line writebacks; 123 blocks (bin is
                                      // occupancy-insensitive, r0/r1 evidence)

__device__ inline __half2 as_h2(unsigned int u) {
    union { unsigned int u; __half2 h; } x; x.u = u; return x.h;
}
__device__ inline unsigned int as_u32(__half2 h) {
    union { unsigned int u; __half2 h; } x; x.h = h; return x.u;
}

// ---- Pass 1: init per-bucket append cursors to b*BCAP ----
__global__ void init_cursor_kernel(int* __restrict__ cursor, int NB) {
    int b = blockIdx.x * blockDim.x + threadIdx.x;
    if (b < NB) cursor[b] = b << BCAP_SHIFT;
}

// ---- zero the sentinel row (index N) of both fp16 state tables ----
__global__ void zero_rows_kernel(unsigned int* __restrict__ SX,
                                 unsigned int* __restrict__ SY, int N) {
    int t = threadIdx.x;   // 32 threads = one 128B row each
    SX[(size_t)N * (DIM / 2) + t] = 0u;
    SY[(size_t)N * (DIM / 2) + t] = 0u;
}

// ---- Pass 2: bin edges into fixed-capacity buckets, packed 4B: src | (dstLocal<<18) ----
__global__ void bin_kernel(const int* __restrict__ src, const int* __restrict__ dst,
                           int* __restrict__ cursor, unsigned int* __restrict__ packed,
                           int E, int NB) {
    __shared__ int lhist[MAXNB];
    __shared__ int lbase[MAXNB];
    const int t = threadIdx.x;
    for (int i = t; i < MAXNB; i += blockDim.x) lhist[i] = 0;
    __syncthreads();
    const long long beg = (long long)blockIdx.x * BIN_CHUNK;
    for (int j = 0; j < BIN_CHUNK / 256; ++j) {
        long long idx = beg + j * 256 + t;
        if (idx < E) atomicAdd(&lhist[dst[idx] >> BNODE_SHIFT], 1);
    }
    __syncthreads();
    for (int b = t; b < NB; b += blockDim.x) {
        int c = lhist[b];
        lbase[b] = c ? atomicAdd(&cursor[b], c) : 0;
    }
    __syncthreads();
    for (int i = t; i < MAXNB; i += blockDim.x) lhist[i] = 0;
    __syncthreads();
    for (int j = 0; j < BIN_CHUNK / 256; ++j) {
        long long idx = beg + j * 256 + t;
        if (idx < E) {
            int d = dst[idx];
            int b = d >> BNODE_SHIFT;
            int lpos = atomicAdd(&lhist[b], 1);
            packed[lbase[b] + lpos] =
                (unsigned int)src[idx] | ((unsigned int)(d & (BNODE - 1)) << 18);
        }
    }
}

// ---- Pass 3: per-bucket exact CSR (padded layout); desc in NODE ORDER ----
__global__ void __launch_bounds__(BNODE) csr_kernel(
        const int* __restrict__ cursor, const unsigned int* __restrict__ packed,
        int* __restrict__ csr_src, float* __restrict__ dinv,
        int4* __restrict__ desc, int N) {
    __shared__ int hist[BNODE];
    __shared__ int s[BNODE];
    const int t = threadIdx.x;
    const int b = blockIdx.x;
    const int b0 = b << BCAP_SHIFT;
    const int cnt = cursor[b] - b0;
    hist[t] = 0;
    __syncthreads();
    for (int i = t; i < cnt; i += BNODE)
        atomicAdd(&hist[packed[b0 + i] >> 18], 1);
    __syncthreads();
    s[t] = hist[t];
    __syncthreads();
    for (int off = 1; off < BNODE; off <<= 1) {
        int v = s[t];
        int a = (t >= off) ? s[t - off] : 0;
        __syncthreads();
        s[t] = v + a;
        __syncthreads();
    }
    const int deg = hist[t];
    const int excl = s[t] - deg;
    const int myBeg = b0 + excl;
    const int node = (b << BNODE_SHIFT) + t;
    if (node < N) {
        float fd = (float)deg;
        float di2 = deg > 0 ? 1.0f / fd : 0.0f;
        dinv[node] = deg > 0 ? rsqrtf(fd) : 0.0f;
        desc[node] = make_int4(myBeg, myBeg + deg, deg, __float_as_int(di2));
    }
    __syncthreads();
    s[t] = excl;   // per-node CSR cursor
    __syncthreads();
    for (int i = t; i < cnt; i += BNODE) {
        unsigned int p = packed[b0 + i];
        int lpos = atomicAdd(&s[p >> 18], 1);
        csr_src[b0 + lpos] = (int)(p & 0x3FFFFu);
    }
}

// ---- conv0: out_emb0 = emb0 (fp32 copy), S0 = fp16(dinv * emb0) ----
__global__ void conv0_kernel(const float* __restrict__ emb0, const float* __restrict__ dinv,
                             float* __restrict__ out_emb0, unsigned int* __restrict__ S0,
                             int n4) {
    int i = blockIdx.x * blockDim.x + threadIdx.x;
    if (i >= n4) return;
    float4 v = ((const float4*)emb0)[i];
    ((float4*)out_emb0)[i] = v;
    float w = dinv[i >> 4];
    uint2 o;
    o.x = as_u32(__float22half2_rn(make_float2(w * v.x, w * v.y)));
    o.y = as_u32(__float22half2_rn(make_float2(w * v.z, w * v.w)));
    ((uint2*)S0)[i] = o;
}

// ---- gather: ONE NODE PER WAVE. Lanes = 8 edge-slots x 8 row-chunks.
// 4-deep predicated unroll; OOB slots read the zeroed sentinel row N.
// !LAST: S_out[node] = fp16(di2 * sum). LAST: fused final combine:
//   acc[node] = 0.25*(emb0 + rs*(S1+S2) + dinv*sum)  (no S3 materialized).
template<bool LAST>
__global__ void gather_kernel(const int4* __restrict__ desc,
                              const int* __restrict__ csr_src,
                              const unsigned int* __restrict__ S_in,
                              unsigned int* __restrict__ S_out,
                              const unsigned int* __restrict__ S1,
                              const float* __restrict__ emb0,
                              float* __restrict__ acc,
                              int N) {
    const int node = (blockIdx.x * blockDim.x + threadIdx.x) >> 6;
    if (node >= N) return;
    const int lane = threadIdx.x & 63;
    const int eg = lane >> 3;      // edge slot 0..7
    const int q  = lane & 7;       // 16B chunk 0..7 of the 128B row
    const int4 d = desc[node];
    const int end = d.y;
    __half2 a0 = as_h2(0u), a1 = as_h2(0u), a2 = as_h2(0u), a3 = as_h2(0u);
    for (int i0 = d.x + eg; i0 < end; i0 += 32) {
        int r0 = csr_src[i0];
        int r1 = csr_src[i0 + 8];
        int r2 = csr_src[i0 + 16];
        int r3 = csr_src[i0 + 24];
        int s0 = r0;
        int s1 = (i0 + 8  < end) ? r1 : N;
        int s2 = (i0 + 16 < end) ? r2 : N;
        int s3 = (i0 + 24 < end) ? r3 : N;
        uint4 g0 = *(const uint4*)(S_in + (size_t)s0 * (DIM / 2) + q * 4);
        uint4 g1 = *(const uint4*)(S_in + (size_t)s1 * (DIM / 2) + q * 4);
        uint4 g2 = *(const uint4*)(S_in + (size_t)s2 * (DIM / 2) + q * 4);
        uint4 g3 = *(const uint4*)(S_in + (size_t)s3 * (DIM / 2) + q * 4);
        a0 = __hadd2(a0, as_h2(g0.x)); a1 = __hadd2(a1, as_h2(g0.y));
        a2 = __hadd2(a2, as_h2(g0.z)); a3 = __hadd2(a3, as_h2(g0.w));
        a0 = __hadd2(a0, as_h2(g1.x)); a1 = __hadd2(a1, as_h2(g1.y));
        a2 = __hadd2(a2, as_h2(g1.z)); a3 = __hadd2(a3, as_h2(g1.w));
        a0 = __hadd2(a0, as_h2(g2.x)); a1 = __hadd2(a1, as_h2(g2.y));
        a2 = __hadd2(a2, as_h2(g2.z)); a3 = __hadd2(a3, as_h2(g2.w));
        a0 = __hadd2(a0, as_h2(g3.x)); a1 = __hadd2(a1, as_h2(g3.y));
        a2 = __hadd2(a2, as_h2(g3.z)); a3 = __hadd2(a3, as_h2(g3.w));
    }
    #pragma unroll
    for (int m = 8; m < 64; m <<= 1) {
        a0 = __hadd2(a0, as_h2(__shfl_xor(as_u32(a0), m, 64)));
        a1 = __hadd2(a1, as_h2(__shfl_xor(as_u32(a1), m, 64)));
        a2 = __hadd2(a2, as_h2(__shfl_xor(as_u32(a2), m, 64)));
        a3 = __hadd2(a3, as_h2(__shfl_xor(as_u32(a3), m, 64)));
    }
    if (lane >= 8) return;
    const float di2 = __int_as_float(d.w);
    float2 f0 = __half22float2(a0);
    float2 f1 = __half22float2(a1);
    float2 f2 = __half22float2(a2);
    float2 f3 = __half22float2(a3);
    if (!LAST) {
        uint4 o;
        o.x = as_u32(__float22half2_rn(make_float2(di2 * f0.x, di2 * f0.y)));
        o.y = as_u32(__float22half2_rn(make_float2(di2 * f1.x, di2 * f1.y)));
        o.z = as_u32(__float22half2_rn(make_float2(di2 * f2.x, di2 * f2.y)));
        o.w = as_u32(__float22half2_rn(make_float2(di2 * f3.x, di2 * f3.y)));
        *(uint4*)(S_out + (size_t)node * (DIM / 2) + lane * 4) = o;
    } else {
        float rs = di2 > 0.f ? rsqrtf(di2) : 0.f;   // sqrt(deg)
        float dv = sqrtf(di2);                      // dinv
        uint4 u1 = *(const uint4*)(S1   + (size_t)node * (DIM / 2) + lane * 4);
        uint4 u2 = *(const uint4*)(S_in + (size_t)node * (DIM / 2) + lane * 4);
        float2 b0 = __half22float2(as_h2(u1.x)), c0 = __half22float2(as_h2(u2.x));
        float2 b1 = __half22float2(as_h2(u1.y)), c1 = __half22float2(as_h2(u2.y));
        float2 b2 = __half22float2(as_h2(u1.z)), c2 = __half22float2(as_h2(u2.z));
        float2 b3 = __half22float2(as_h2(u1.w)), c3 = __half22float2(as_h2(u2.w));
        const float* e = emb0 + (size_t)node * DIM + lane * 8;
        float4 e0 = *(const float4*)(e);
        float4 e1 = *(const float4*)(e + 4);
        float4 o0, o1;
        o0.x = 0.25f * (e0.x + rs * (b0.x + c0.x) + dv * f0.x);
        o0.y = 0.25f * (e0.y + rs * (b0.y + c0.y) + dv * f0.y);
        o0.z = 0.25f * (e0.z + rs * (b1.x + c1.x) + dv * f1.x);
        o0.w = 0.25f * (e0.w + rs * (b1.y + c1.y) + dv * f1.y);
        o1.x = 0.25f * (e1.x + rs * (b2.x + c2.x) + dv * f2.x);
        o1.y = 0.25f * (e1.y + rs * (b2.y + c2.y) + dv * f2.y);
        o1.z = 0.25f * (e1.z + rs * (b3.x + c3.x) + dv * f3.x);
        o1.w = 0.25f * (e1.w + rs * (b3.y + c3.y) + dv * f3.y);
        float* ap = acc + (size_t)node * DIM + lane * 8;
        *(float4*)(ap) = o0;
        *(float4*)(ap + 4) = o1;
    }
}

static inline size_t align256(size_t x) { return (x + 255) & ~(size_t)255; }

extern "C" void kernel_launch(void* const* d_in, const int* in_sizes, int n_in,
                              void* d_out, int out_size, void* d_ws, size_t ws_size,
                              hipStream_t stream) {
    const int*   edge = (const int*)d_in[0];
    const float* emb0 = (const float*)d_in[1];
    const int E = in_sizes[0] / 2;
    const int N = in_sizes[1] / DIM;
    const int* src = edge;
    const int* dst = edge + E;
    const int NB = (N + BNODE - 1) >> BNODE_SHIFT;   // 782 for N=200000

    // workspace carve-up (~107 MB)
    char* ws = (char*)d_ws;
    int* cursor        = (int*)ws;  ws += align256((size_t)(MAXNB + 1) * sizeof(int));
    float* dinv        = (float*)ws; ws += align256((size_t)N * sizeof(float));
    int4* desc         = (int4*)ws; ws += align256((size_t)N * sizeof(int4));
    unsigned int* packed = (unsigned int*)ws; ws += align256((size_t)NB * BCAP * sizeof(int));
    int* csr_src       = (int*)ws;  ws += align256(((size_t)NB * BCAP + 64) * sizeof(int));
    unsigned int* SX   = (unsigned int*)ws; ws += align256((size_t)(N + 1) * (DIM / 2) * sizeof(unsigned int));
    unsigned int* SY   = (unsigned int*)ws; ws += align256((size_t)(N + 1) * (DIM / 2) * sizeof(unsigned int));

    float* out_emb0 = (float*)d_out;
    float* acc      = out_emb0 + (size_t)N * DIM;

    const int blocks_e = (int)(((long long)E + BIN_CHUNK - 1) / BIN_CHUNK);
    const int n4 = N * DIM / 4;

    init_cursor_kernel<<<(NB + 255) / 256, 256, 0, stream>>>(cursor, NB);
    zero_rows_kernel<<<1, 32, 0, stream>>>(SX, SY, N);
    bin_kernel<<<blocks_e, 256, 0, stream>>>(src, dst, cursor, packed, E, NB);
    csr_kernel<<<NB, BNODE, 0, stream>>>(cursor, packed, csr_src, dinv, desc, N);

    conv0_kernel<<<(n4 + 255) / 256, 256, 0, stream>>>(emb0, dinv, out_emb0, SX, n4);

    const long long gthreads = (long long)N * 64;   // one wave per node
    const int ggrid = (int)((gthreads + 255) / 256);
    // S0=SX -> S1=SY -> S2=SX (S0 dead) -> fused finale (no S3 write)
    gather_kernel<false><<<ggrid, 256, 0, stream>>>(desc, csr_src, SX, SY, nullptr, nullptr, nullptr, N);
    gather_kernel<false><<<ggrid, 256, 0, stream>>>(desc, csr_src, SY, SX, nullptr, nullptr, nullptr, N);
    gather_kernel<true><<<ggrid, 256, 0, stream>>>(desc, csr_src, SX, nullptr, SY, emb0, acc, N);
}

// Round 7
// 489.469 us; speedup vs baseline: 1.2058x; 1.2058x over previous
//
#include <hip/hip_runtime.h>
#include <hip/hip_fp16.h>

#define DIM 64
#define BNODE_SHIFT 8                 // 256 nodes per bucket
#define BNODE (1 << BNODE_SHIFT)
#define MAXNB 1024                    // max buckets (N <= 262144)
#define BCAP_SHIFT 13                 // 8192-edge capacity per bucket (mean 5115, sigma ~72)
#define BCAP (1 << BCAP_SHIFT)
#define BIN_MAXCHUNK 16384            // staging capacity per block (u16 ranks)

__device__ inline __half2 as_h2(unsigned int u) {
    union { unsigned int u; __half2 h; } x; x.u = u; return x.h;
}
__device__ inline unsigned int as_u32(__half2 h) {
    union { unsigned int u; __half2 h; } x; x.h = h; return x.u;
}

// ---- Pass 1: init per-bucket append cursors to b*BCAP ----
__global__ void init_cursor_kernel(int* __restrict__ cursor, int NB) {
    int b = blockIdx.x * blockDim.x + threadIdx.x;
    if (b < NB) cursor[b] = b << BCAP_SHIFT;
}

// ---- zero the sentinel row (index N) of both fp16 state tables ----
__global__ void zero_rows_kernel(unsigned int* __restrict__ SX,
                                 unsigned int* __restrict__ SY, int N) {
    int t = threadIdx.x;   // 32 threads = one 128B row each
    SX[(size_t)N * (DIM / 2) + t] = 0u;
    SY[(size_t)N * (DIM / 2) + t] = 0u;
}

// ---- bin3: ONE returning-atomic pass + rank staging; placement pass is atomic-free.
// Grid ~256 blocks (1/CU): atomic wall = CHUNK*8cyc ~ 52us; run length ~20 edges
// keeps dirty-line writeback ~40MB (~36us wall). Both walls met simultaneously.
__global__ void __launch_bounds__(512) bin3_kernel(
        const int* __restrict__ src, const int* __restrict__ dst,
        int* __restrict__ cursor, unsigned int* __restrict__ packed,
        int E, int NB, int CHUNK) {
    __shared__ int lhist[MAXNB];
    __shared__ int lbase[MAXNB];
    __shared__ unsigned short srank[BIN_MAXCHUNK];   // 32KB: per-edge rank from pass 1
    const int t = threadIdx.x;
    for (int i = t; i < MAXNB; i += 512) lhist[i] = 0;
    __syncthreads();
    const long long beg = (long long)blockIdx.x * CHUNK;
    long long lim = beg + CHUNK;
    if (lim > E) lim = E;
    // pass 1: count + stage rank (single returning LDS atomic per edge)
    for (long long idx = beg + t; idx < lim; idx += 512) {
        int d = dst[idx];
        int c = atomicAdd(&lhist[d >> BNODE_SHIFT], 1);
        srank[(int)(idx - beg)] = (unsigned short)c;
    }
    __syncthreads();
    // reserve contiguous bucket space (tiny global atomic pass)
    for (int b = t; b < NB; b += 512) {
        int c = lhist[b];
        lbase[b] = c ? atomicAdd(&cursor[b], c) : 0;
    }
    __syncthreads();
    // pass 2: place (no atomics; dst/src re-read are coalesced + L2-hot)
    for (long long idx = beg + t; idx < lim; idx += 512) {
        int d = dst[idx];
        int b = d >> BNODE_SHIFT;
        int c = srank[(int)(idx - beg)];
        packed[lbase[b] + c] =
            (unsigned int)src[idx] | ((unsigned int)(d & (BNODE - 1)) << 18);
    }
}

// ---- csr3: per-bucket exact CSR; hist pass returns within-node rank (staged u16),
// scatter pass is atomic-free. desc in NODE ORDER. ----
__global__ void __launch_bounds__(BNODE) csr3_kernel(
        const int* __restrict__ cursor, const unsigned int* __restrict__ packed,
        int* __restrict__ csr_src, float* __restrict__ dinv,
        int4* __restrict__ desc, int N) {
    __shared__ int hist[BNODE];
    __shared__ int s[BNODE];
    __shared__ int soff[BNODE];
    __shared__ unsigned short rnk[BCAP];   // 16KB: per-edge within-node rank
    const int t = threadIdx.x;
    const int b = blockIdx.x;
    const int b0 = b << BCAP_SHIFT;
    const int cnt = cursor[b] - b0;
    hist[t] = 0;
    __syncthreads();
    for (int i = t; i < cnt; i += BNODE) {
        int c = atomicAdd(&hist[packed[b0 + i] >> 18], 1);
        rnk[i] = (unsigned short)c;
    }
    __syncthreads();
    s[t] = hist[t];
    __syncthreads();
    for (int off = 1; off < BNODE; off <<= 1) {
        int v = s[t];
        int a = (t >= off) ? s[t - off] : 0;
        __syncthreads();
        s[t] = v + a;
        __syncthreads();
    }
    const int deg = hist[t];
    const int excl = s[t] - deg;
    soff[t] = excl;
    const int myBeg = b0 + excl;
    const int node = (b << BNODE_SHIFT) + t;
    if (node < N) {
        float fd = (float)deg;
        float di2 = deg > 0 ? 1.0f / fd : 0.0f;
        dinv[node] = deg > 0 ? rsqrtf(fd) : 0.0f;
        desc[node] = make_int4(myBeg, myBeg + deg, deg, __float_as_int(di2));
    }
    __syncthreads();
    // scatter pass: position = soff[node] + staged rank (no atomics)
    for (int i = t; i < cnt; i += BNODE) {
        unsigned int p = packed[b0 + i];
        csr_src[b0 + soff[p >> 18] + rnk[i]] = (int)(p & 0x3FFFFu);
    }
}

// ---- conv0: out_emb0 = emb0 (fp32 copy), S0 = fp16(dinv * emb0) ----
__global__ void conv0_kernel(const float* __restrict__ emb0, const float* __restrict__ dinv,
                             float* __restrict__ out_emb0, unsigned int* __restrict__ S0,
                             int n4) {
    int i = blockIdx.x * blockDim.x + threadIdx.x;
    if (i >= n4) return;
    float4 v = ((const float4*)emb0)[i];
    ((float4*)out_emb0)[i] = v;
    float w = dinv[i >> 4];
    uint2 o;
    o.x = as_u32(__float22half2_rn(make_float2(w * v.x, w * v.y)));
    o.y = as_u32(__float22half2_rn(make_float2(w * v.z, w * v.w)));
    ((uint2*)S0)[i] = o;
}

// ---- gather: ONE NODE PER WAVE. Lanes = 8 edge-slots x 8 row-chunks.
// 4-deep predicated unroll; OOB slots read the zeroed sentinel row N.
// !LAST: S_out[node] = fp16(di2 * sum). LAST: fused final combine:
//   acc[node] = 0.25*(emb0 + rs*(S1+S2) + dinv*sum)  (no S3 materialized).
template<bool LAST>
__global__ void gather_kernel(const int4* __restrict__ desc,
                              const int* __restrict__ csr_src,
                              const unsigned int* __restrict__ S_in,
                              unsigned int* __restrict__ S_out,
                              const unsigned int* __restrict__ S1,
                              const float* __restrict__ emb0,
                              float* __restrict__ acc,
                              int N) {
    const int node = (blockIdx.x * blockDim.x + threadIdx.x) >> 6;
    if (node >= N) return;
    const int lane = threadIdx.x & 63;
    const int eg = lane >> 3;      // edge slot 0..7
    const int q  = lane & 7;       // 16B chunk 0..7 of the 128B row
    const int4 d = desc[node];
    const int end = d.y;
    __half2 a0 = as_h2(0u), a1 = as_h2(0u), a2 = as_h2(0u), a3 = as_h2(0u);
    for (int i0 = d.x + eg; i0 < end; i0 += 32) {
        int r0 = csr_src[i0];
        int r1 = csr_src[i0 + 8];
        int r2 = csr_src[i0 + 16];
        int r3 = csr_src[i0 + 24];
        int s0 = r0;
        int s1 = (i0 + 8  < end) ? r1 : N;
        int s2 = (i0 + 16 < end) ? r2 : N;
        int s3 = (i0 + 24 < end) ? r3 : N;
        uint4 g0 = *(const uint4*)(S_in + (size_t)s0 * (DIM / 2) + q * 4);
        uint4 g1 = *(const uint4*)(S_in + (size_t)s1 * (DIM / 2) + q * 4);
        uint4 g2 = *(const uint4*)(S_in + (size_t)s2 * (DIM / 2) + q * 4);
        uint4 g3 = *(const uint4*)(S_in + (size_t)s3 * (DIM / 2) + q * 4);
        a0 = __hadd2(a0, as_h2(g0.x)); a1 = __hadd2(a1, as_h2(g0.y));
        a2 = __hadd2(a2, as_h2(g0.z)); a3 = __hadd2(a3, as_h2(g0.w));
        a0 = __hadd2(a0, as_h2(g1.x)); a1 = __hadd2(a1, as_h2(g1.y));
        a2 = __hadd2(a2, as_h2(g1.z)); a3 = __hadd2(a3, as_h2(g1.w));
        a0 = __hadd2(a0, as_h2(g2.x)); a1 = __hadd2(a1, as_h2(g2.y));
        a2 = __hadd2(a2, as_h2(g2.z)); a3 = __hadd2(a3, as_h2(g2.w));
        a0 = __hadd2(a0, as_h2(g3.x)); a1 = __hadd2(a1, as_h2(g3.y));
        a2 = __hadd2(a2, as_h2(g3.z)); a3 = __hadd2(a3, as_h2(g3.w));
    }
    #pragma unroll
    for (int m = 8; m < 64; m <<= 1) {
        a0 = __hadd2(a0, as_h2(__shfl_xor(as_u32(a0), m, 64)));
        a1 = __hadd2(a1, as_h2(__shfl_xor(as_u32(a1), m, 64)));
        a2 = __hadd2(a2, as_h2(__shfl_xor(as_u32(a2), m, 64)));
        a3 = __hadd2(a3, as_h2(__shfl_xor(as_u32(a3), m, 64)));
    }
    if (lane >= 8) return;
    const float di2 = __int_as_float(d.w);
    float2 f0 = __half22float2(a0);
    float2 f1 = __half22float2(a1);
    float2 f2 = __half22float2(a2);
    float2 f3 = __half22float2(a3);
    if (!LAST) {
        uint4 o;
        o.x = as_u32(__float22half2_rn(make_float2(di2 * f0.x, di2 * f0.y)));
        o.y = as_u32(__float22half2_rn(make_float2(di2 * f1.x, di2 * f1.y)));
        o.z = as_u32(__float22half2_rn(make_float2(di2 * f2.x, di2 * f2.y)));
        o.w = as_u32(__float22half2_rn(make_float2(di2 * f3.x, di2 * f3.y)));
        *(uint4*)(S_out + (size_t)node * (DIM / 2) + lane * 4) = o;
    } else {
        float rs = di2 > 0.f ? rsqrtf(di2) : 0.f;   // sqrt(deg)
        float dv = sqrtf(di2);                      // dinv
        uint4 u1 = *(const uint4*)(S1   + (size_t)node * (DIM / 2) + lane * 4);
        uint4 u2 = *(const uint4*)(S_in + (size_t)node * (DIM / 2) + lane * 4);
        float2 b0 = __half22float2(as_h2(u1.x)), c0 = __half22float2(as_h2(u2.x));
        float2 b1 = __half22float2(as_h2(u1.y)), c1 = __half22float2(as_h2(u2.y));
        float2 b2 = __half22float2(as_h2(u1.z)), c2 = __half22float2(as_h2(u2.z));
        float2 b3 = __half22float2(as_h2(u1.w)), c3 = __half22float2(as_h2(u2.w));
        const float* e = emb0 + (size_t)node * DIM + lane * 8;
        float4 e0 = *(const float4*)(e);
        float4 e1 = *(const float4*)(e + 4);
        float4 o0, o1;
        o0.x = 0.25f * (e0.x + rs * (b0.x + c0.x) + dv * f0.x);
        o0.y = 0.25f * (e0.y + rs * (b0.y + c0.y) + dv * f0.y);
        o0.z = 0.25f * (e0.z + rs * (b1.x + c1.x) + dv * f1.x);
        o0.w = 0.25f * (e0.w + rs * (b1.y + c1.y) + dv * f1.y);
        o1.x = 0.25f * (e1.x + rs * (b2.x + c2.x) + dv * f2.x);
        o1.y = 0.25f * (e1.y + rs * (b2.y + c2.y) + dv * f2.y);
        o1.z = 0.25f * (e1.z + rs * (b3.x + c3.x) + dv * f3.x);
        o1.w = 0.25f * (e1.w + rs * (b3.y + c3.y) + dv * f3.y);
        float* ap = acc + (size_t)node * DIM + lane * 8;
        *(float4*)(ap) = o0;
        *(float4*)(ap + 4) = o1;
    }
}

static inline size_t align256(size_t x) { return (x + 255) & ~(size_t)255; }

extern "C" void kernel_launch(void* const* d_in, const int* in_sizes, int n_in,
                              void* d_out, int out_size, void* d_ws, size_t ws_size,
                              hipStream_t stream) {
    const int*   edge = (const int*)d_in[0];
    const float* emb0 = (const float*)d_in[1];
    const int E = in_sizes[0] / 2;
    const int N = in_sizes[1] / DIM;
    const int* src = edge;
    const int* dst = edge + E;
    const int NB = (N + BNODE - 1) >> BNODE_SHIFT;   // 782 for N=200000

    // bin3 grid: >=256 blocks, chunk capped at staging capacity (16384)
    int bin_blocks = 256;
    int chunk = (E + bin_blocks - 1) / bin_blocks;          // 15625 for E=4M
    if (chunk > BIN_MAXCHUNK) {
        bin_blocks = (E + BIN_MAXCHUNK - 1) / BIN_MAXCHUNK;
        chunk = (E + bin_blocks - 1) / bin_blocks;
    }

    // workspace carve-up (~107 MB)
    char* ws = (char*)d_ws;
    int* cursor        = (int*)ws;  ws += align256((size_t)(MAXNB + 1) * sizeof(int));
    float* dinv        = (float*)ws; ws += align256((size_t)N * sizeof(float));
    int4* desc         = (int4*)ws; ws += align256((size_t)N * sizeof(int4));
    unsigned int* packed = (unsigned int*)ws; ws += align256((size_t)NB * BCAP * sizeof(int));
    int* csr_src       = (int*)ws;  ws += align256(((size_t)NB * BCAP + 64) * sizeof(int));
    unsigned int* SX   = (unsigned int*)ws; ws += align256((size_t)(N + 1) * (DIM / 2) * sizeof(unsigned int));
    unsigned int* SY   = (unsigned int*)ws; ws += align256((size_t)(N + 1) * (DIM / 2) * sizeof(unsigned int));

    float* out_emb0 = (float*)d_out;
    float* acc      = out_emb0 + (size_t)N * DIM;

    const int n4 = N * DIM / 4;

    init_cursor_kernel<<<(NB + 255) / 256, 256, 0, stream>>>(cursor, NB);
    zero_rows_kernel<<<1, 32, 0, stream>>>(SX, SY, N);
    bin3_kernel<<<bin_blocks, 512, 0, stream>>>(src, dst, cursor, packed, E, NB, chunk);
    csr3_kernel<<<NB, BNODE, 0, stream>>>(cursor, packed, csr_src, dinv, desc, N);

    conv0_kernel<<<(n4 + 255) / 256, 256, 0, stream>>>(emb0, dinv, out_emb0, SX, n4);

    const long long gthreads = (long long)N * 64;   // one wave per node
    const int ggrid = (int)((gthreads + 255) / 256);
    // S0=SX -> S1=SY -> S2=SX (S0 dead) -> fused finale (no S3 write)
    gather_kernel<false><<<ggrid, 256, 0, stream>>>(desc, csr_src, SX, SY, nullptr, nullptr, nullptr, N);
    gather_kernel<false><<<ggrid, 256, 0, stream>>>(desc, csr_src, SY, SX, nullptr, nullptr, nullptr, N);
    gather_kernel<true><<<ggrid, 256, 0, stream>>>(desc, csr_src, SX, nullptr, SY, emb0, acc, N);
}